// Round 5
// baseline (76.643 us; speedup 1.0000x reference)
//
#include <hip/hip_runtime.h>

#define NNODES 2048
#define NHEADS 8
#define NN (NNODES * NNODES)

#define WINNER_BYTES ((size_t)NN * sizeof(int))  // 16 MiB

// Pass 1 (after memsets): resolve duplicate (row,col) scatters as
// last-edge-index-wins (matches numpy fancy-assignment scatter-set).
__global__ __launch_bounds__(256) void edge_max_kernel(const int* __restrict__ ei,
                                                       int E,
                                                       int* __restrict__ winner) {
    int e = blockIdx.x * blockDim.x + threadIdx.x;
    if (e >= E) return;
    const int row = ei[e];
    const int col = ei[E + e];
    atomicMax(&winner[row * NNODES + col], e);
}

// Pass 2: sparse scatter. Each edge checks if it won its cell; winners
// compute the 8 sigmoids and store 8 scattered dwords into the pre-zeroed
// (H, N, N) output. ~262K winners -> ~2M scattered stores total.
__global__ __launch_bounds__(256) void scatter_kernel(const int* __restrict__ ei,
                                                      const float* __restrict__ edge_score,
                                                      const float* __restrict__ W,
                                                      const float* __restrict__ b,
                                                      int E,
                                                      const int* __restrict__ winner,
                                                      float* __restrict__ out) {
    int e = blockIdx.x * blockDim.x + threadIdx.x;
    if (e >= E) return;
    const int row = ei[e];
    const int col = ei[E + e];
    const int cell = row * NNODES + col;
    if (winner[cell] != e) return;  // a later duplicate edge owns this cell

    const float fr = (float)row, fc = (float)col, sc = edge_score[e];
#pragma unroll
    for (int h = 0; h < NHEADS; ++h) {
        const float x = fmaf(fr, W[3 * h + 0],
                        fmaf(fc, W[3 * h + 1],
                        fmaf(sc, W[3 * h + 2], b[h])));
        const float s = 1.0f / (1.0f + __expf(-x));
        out[(size_t)h * NN + cell] = s;
    }
}

extern "C" void kernel_launch(void* const* d_in, const int* in_sizes, int n_in,
                              void* d_out, int out_size, void* d_ws, size_t ws_size,
                              hipStream_t stream) {
    const int*   edge_index = (const int*)d_in[0];   // (2, E) int32
    const float* edge_score = (const float*)d_in[1]; // (E,)
    const float* W          = (const float*)d_in[2]; // (H, 3)
    const float* b          = (const float*)d_in[3]; // (H,)
    float*       out        = (float*)d_out;         // (H, N, N)
    const int E = in_sizes[1];

    int* winner = (int*)d_ws;  // 16 MiB scratch

    // Bulk data movement via the runtime's fill (measured 6.7-6.9 TB/s).
    hipMemsetAsync(winner, 0xFF, WINNER_BYTES, stream);          // winner = -1
    hipMemsetAsync(out, 0, (size_t)out_size * sizeof(float), stream);  // out = 0

    const int blocks = (E + 255) / 256;
    edge_max_kernel<<<blocks, 256, 0, stream>>>(edge_index, E, winner);
    scatter_kernel<<<blocks, 256, 0, stream>>>(edge_index, edge_score, W, b,
                                               E, winner, out);
}